// Round 8
// baseline (7214.697 us; speedup 1.0000x reference)
//
#include <hip/hip_runtime.h>

#define B_ 128
#define T_ 1024
#define I_ 256
#define H_ 512
#define O_ 128

#define BGROUPS 4
#define ROWS 32                   // batch rows per block
#define CGROUPS 16
#define HC 32                     // h-cols per block
#define NBLK (BGROUPS*CGROUPS)    // 64 blocks
#define NTHR 512                  // 8 waves: (kh 0..1) x (nh 0..1) x (mt 0..1)

#define HSLAB32 (B_*(H_/2))       // u32 per h slab: 32768
#define FLAGW 64                  // flag words per (t, group)
#define WS_INIT_BYTES ((2*HSLAB32 + T_*BGROUPS*FLAGW)*4)   // 1.25 MB

typedef __attribute__((ext_vector_type(8))) short short8;
typedef __attribute__((ext_vector_type(4))) float f32x4;

__device__ __forceinline__ unsigned int bf16rne(float f) {
    unsigned int u = __builtin_bit_cast(unsigned int, f);
    u += 0x7fffu + ((u >> 16) & 1u);
    return u >> 16;
}
__device__ __forceinline__ short8 pack8(float4 a, float4 b) {
    short8 r;
    r[0]=(short)bf16rne(a.x); r[1]=(short)bf16rne(a.y); r[2]=(short)bf16rne(a.z); r[3]=(short)bf16rne(a.w);
    r[4]=(short)bf16rne(b.x); r[5]=(short)bf16rne(b.y); r[6]=(short)bf16rne(b.z); r[7]=(short)bf16rne(b.w);
    return r;
}
__device__ __forceinline__ short8 cvt8(const float* p) {
    return pack8(*(const float4*)p, *(const float4*)(p + 4));
}
__device__ __forceinline__ unsigned long long ald64(const unsigned long long* p) {
    return __hip_atomic_load(p, __ATOMIC_RELAXED, __HIP_MEMORY_SCOPE_AGENT);
}

__global__ __launch_bounds__(NTHR, 1)
void gru_mfma(const float* __restrict__ x,
              const float* __restrict__ Wih,
              const float* __restrict__ Whh,
              const float* __restrict__ bih,
              const float* __restrict__ bhh,
              unsigned int* __restrict__ hslab,   // [2][128][256] u32 (bf16 pairs)
              unsigned int* __restrict__ flags)   // [1024][4][64]
{
    __shared__ __align__(16) f32x4 cdump[4][4][64];   // [pair][acc][lane] = 16 KB

    const int tid  = threadIdx.x;
    const int lane = tid & 63;
    const int g    = blockIdx.x >> 4;          // batch group 0..3
    const int cg   = blockIdx.x & 15;          // column group 0..15
    const int rb0  = g * ROWS;
    const int hc0  = cg * HC;

    const int wv   = tid >> 6;                 // 0..7
    const int mt   = wv & 1;                   // row half (16 rows)
    const int nh   = (wv >> 1) & 1;            // col half (16 cols)
    const int kh   = wv >> 2;                  // K half
    const int pair = nh * 2 + mt;              // dump region shared by kh0/kh1 partners

    // ---- one-time: weight B-fragments into registers (full tile, half K) ----
    // B-frag: lane l holds W[col = coln][k = ktile*32 + (l>>4)*8 .. +8]
    const int coln = hc0 + nh * 16 + (lane & 15);
    short8 BX[4][3], BH[8][3];
#pragma unroll
    for (int xk = 0; xk < 4; ++xk) {
        int kb = kh * 128 + xk * 32 + ((lane >> 4) << 3);
#pragma unroll
        for (int nt = 0; nt < 3; ++nt)
            BX[xk][nt] = cvt8(Wih + (nt * H_ + coln) * I_ + kb);
    }
#pragma unroll
    for (int hk = 0; hk < 8; ++hk) {
        int kb = kh * 256 + hk * 32 + ((lane >> 4) << 3);
#pragma unroll
        for (int nt = 0; nt < 3; ++nt)
            BH[hk][nt] = cvt8(Whh + (nt * H_ + coln) * H_ + kb);
    }

    // A-frag geometry
    const int arow = rb0 + mt * 16 + (lane & 15);
    const int hfo  = arow * (H_ / 2) + ((lane >> 4) << 2);   // u32 idx; + ktile*16

    // finalize constants (kh0 lanes): rows mt*16+(lane>>4)*4+i, col = coln
    const float bR  = bih[coln] + bhh[coln];
    const float bZ  = bih[H_ + coln] + bhh[H_ + coln];
    const float bNx = bih[2 * H_ + coln];
    const float bNh = bhh[2 * H_ + coln];
    float hprev[4] = {0.f, 0.f, 0.f, 0.f};

    // x prefetch: this wave's 4 k-tiles (32 floats)
    const float* xbase = x + (arow * T_) * I_ + kh * 128 + ((lane >> 4) << 3);
    float4 px[8];
#pragma unroll
    for (int xk = 0; xk < 4; ++xk) {
        px[2*xk]   = *(const float4*)(xbase + xk * 32);
        px[2*xk+1] = *(const float4*)(xbase + xk * 32 + 4);
    }
    xbase += I_;

#pragma unroll 1
    for (int t = 0; t < T_; ++t) {
        // ---- detect: every wave polls all 64 group flags (lane -> word) ----
        if (t > 0) {
            const unsigned int* fl = flags + ((t - 1) * BGROUPS + g) * FLAGW;
            unsigned int fv;
            do {
                fv = __hip_atomic_load(fl + lane, __ATOMIC_RELAXED, __HIP_MEMORY_SCOPE_AGENT);
            } while (!__all((int)(fv != 0)));
        }
        asm volatile("" ::: "memory");         // keep h loads below the poll

        // ---- h fragment loads (flag guarantees data landed: first-try fresh) ----
        const unsigned int* hb = hslab + (t & 1) * HSLAB32 + hfo;
        unsigned long long hv[16];
#pragma unroll
        for (int hk = 0; hk < 8; ++hk) {
            const unsigned long long* p = (const unsigned long long*)(hb + (kh * 8 + hk) * 16);
            hv[2*hk]   = ald64(p);
            hv[2*hk+1] = ald64(p + 1);
        }

        // ---- x part (prefetched regs) while h loads fly ----
        f32x4 accR = {0.f,0.f,0.f,0.f}, accZ = accR, accNX = accR, accNH = accR;
#pragma unroll
        for (int xk = 0; xk < 4; ++xk) {
            short8 ax = pack8(px[2*xk], px[2*xk+1]);
            accR  = __builtin_amdgcn_mfma_f32_16x16x32_bf16(ax, BX[xk][0], accR, 0, 0, 0);
            accZ  = __builtin_amdgcn_mfma_f32_16x16x32_bf16(ax, BX[xk][1], accZ, 0, 0, 0);
            accNX = __builtin_amdgcn_mfma_f32_16x16x32_bf16(ax, BX[xk][2], accNX, 0, 0, 0);
        }
        // ---- h part ----
#pragma unroll
        for (int hk = 0; hk < 8; ++hk) {
            union { unsigned long long q[2]; short8 s; } u;
            u.q[0] = hv[2*hk]; u.q[1] = hv[2*hk+1];
            accR  = __builtin_amdgcn_mfma_f32_16x16x32_bf16(u.s, BH[hk][0], accR, 0, 0, 0);
            accZ  = __builtin_amdgcn_mfma_f32_16x16x32_bf16(u.s, BH[hk][1], accZ, 0, 0, 0);
            accNH = __builtin_amdgcn_mfma_f32_16x16x32_bf16(u.s, BH[hk][2], accNH, 0, 0, 0);
        }

        // ---- one-way K-reduce hand-off: kh1 dumps, kh0 finalizes in-register ----
        if (kh == 1) {
            cdump[pair][0][lane] = accR;
            cdump[pair][1][lane] = accZ;
            cdump[pair][2][lane] = accNX;
            cdump[pair][3][lane] = accNH;
        }
        __syncthreads();                       // only barrier per step

        if (kh == 0) {
            f32x4 pR  = cdump[pair][0][lane];
            f32x4 pZ  = cdump[pair][1][lane];
            f32x4 pNX = cdump[pair][2][lane];
            f32x4 pNH = cdump[pair][3][lane];
            unsigned int hb16[4];
#pragma unroll
            for (int i = 0; i < 4; ++i) {
                float sr  = accR[i]  + pR[i]  + bR;
                float sz  = accZ[i]  + pZ[i]  + bZ;
                float sxn = accNX[i] + pNX[i] + bNx;
                float shn = accNH[i] + pNH[i] + bNh;
                float r = 1.f / (1.f + __expf(-sr));
                float z = 1.f / (1.f + __expf(-sz));
                float e2 = __expf(2.f * (sxn + r * shn));
                float n = 1.f - 2.f / (e2 + 1.f);      // tanh, overflow-safe
                float hnew = (1.f - z) * n + z * hprev[i];
                hprev[i] = hnew;
                hb16[i] = bf16rne(hnew);
            }
            unsigned int* hdst = hslab + ((t + 1) & 1) * HSLAB32;
            const int cw   = cg * 16 + nh * 8 + ((lane & 15) >> 1);
            const int rowb = rb0 + mt * 16 + ((lane >> 4) << 2);
#pragma unroll
            for (int i = 0; i < 4; ++i) {
                unsigned int ob = (unsigned int)__shfl_xor((int)hb16[i], 1);
                if (!(lane & 1)) {
                    __hip_atomic_store(hdst + (rowb + i) * (H_ / 2) + cw,
                                       (hb16[i] & 0xffffu) | (ob << 16),
                                       __ATOMIC_RELAXED, __HIP_MEMORY_SCOPE_AGENT);
                }
            }
            // per-wave drain (own h stores) then per-wave flag — no block barrier
            asm volatile("s_waitcnt vmcnt(0)" ::: "memory");
            if (lane == 0)
                __hip_atomic_store(flags + (t * BGROUPS + g) * FLAGW + cg * 4 + pair, 1u,
                                   __ATOMIC_RELAXED, __HIP_MEMORY_SCOPE_AGENT);
        }

        // ---- x prefetch for t+1 (latency hides under next detect) ----
        if (t + 1 < T_) {
#pragma unroll
            for (int xk = 0; xk < 4; ++xk) {
                px[2*xk]   = *(const float4*)(xbase + xk * 32);
                px[2*xk+1] = *(const float4*)(xbase + xk * 32 + 4);
            }
            xbase += I_;
        }
    }
}

__global__ __launch_bounds__(256)
void fc_kernel(const unsigned int* __restrict__ hp,   // hslab[0]: [128][256] u32 bf16-pairs
               const float* __restrict__ fcW,
               const float* __restrict__ fcb,
               float* __restrict__ out)
{
    int gid = blockIdx.x * 256 + threadIdx.x;
    int b = gid >> 7, o = gid & 127;
    const unsigned int* hr = hp + b * (H_ / 2);
    const float* wr = fcW + o * H_;
    float acc = 0.f;
#pragma unroll 8
    for (int i = 0; i < H_ / 2; i += 4) {
        uint4 v = *(const uint4*)(hr + i);
        float4 w0 = *(const float4*)(wr + 2 * i);
        float4 w1 = *(const float4*)(wr + 2 * i + 4);
        acc += __builtin_bit_cast(float, v.x << 16)          * w0.x
             + __builtin_bit_cast(float, v.x & 0xffff0000u)  * w0.y
             + __builtin_bit_cast(float, v.y << 16)          * w0.z
             + __builtin_bit_cast(float, v.y & 0xffff0000u)  * w0.w
             + __builtin_bit_cast(float, v.z << 16)          * w1.x
             + __builtin_bit_cast(float, v.z & 0xffff0000u)  * w1.y
             + __builtin_bit_cast(float, v.w << 16)          * w1.z
             + __builtin_bit_cast(float, v.w & 0xffff0000u)  * w1.w;
    }
    out[gid] = acc + fcb[o];
}

extern "C" void kernel_launch(void* const* d_in, const int* in_sizes, int n_in,
                              void* d_out, int out_size, void* d_ws, size_t ws_size,
                              hipStream_t stream)
{
    const float* x   = (const float*)d_in[0];
    const float* Wih = (const float*)d_in[1];
    const float* Whh = (const float*)d_in[2];
    const float* bih = (const float*)d_in[3];
    const float* bhh = (const float*)d_in[4];
    const float* fcW = (const float*)d_in[5];
    const float* fcb = (const float*)d_in[6];
    float* out = (float*)d_out;

    unsigned int* hslab = (unsigned int*)d_ws;                  // [2][128][256]
    unsigned int* flags = hslab + 2 * HSLAB32;                  // [1024][4][64]

    hipMemsetAsync(d_ws, 0, WS_INIT_BYTES, stream);   // h0 = 0, flags = 0 (every replay)

    hipLaunchKernelGGL(gru_mfma, dim3(NBLK), dim3(NTHR), 0, stream,
                       x, Wih, Whh, bih, bhh, hslab, flags);

    hipLaunchKernelGGL(fc_kernel, dim3((B_ * O_) / 256), dim3(256), 0, stream,
                       hslab, fcW, fcb, out);         // final h is slab 0 (T even)
}

// Round 10
// 4263.863 us; speedup vs baseline: 1.6921x; 1.6921x over previous
//
#include <hip/hip_runtime.h>

#define B_ 128
#define T_ 1024
#define I_ 256
#define H_ 512
#define O_ 128

#define BGROUPS 8
#define ROWS 16                   // batch rows per block (one M-tile)
#define CGROUPS 16
#define HC 32                     // h-cols per block
#define NBLK (BGROUPS*CGROUPS)    // 128
#define NTHR 512                  // 8 waves: (kq 0..3) x (nh 0..1)

#define HSLAB32 (B_*(H_/2))       // u32 per h slab: 32768
#define WS_INIT_BYTES ((2*HSLAB32 + T_*BGROUPS*CGROUPS)*4)   // 786432

typedef __attribute__((ext_vector_type(8))) short short8;
typedef __attribute__((ext_vector_type(4))) float f32x4;

__device__ __forceinline__ unsigned int bf16rne(float f) {
    unsigned int u = __builtin_bit_cast(unsigned int, f);
    u += 0x7fffu + ((u >> 16) & 1u);
    return u >> 16;
}
__device__ __forceinline__ short8 pack8(float4 a, float4 b) {
    short8 r;
    r[0]=(short)bf16rne(a.x); r[1]=(short)bf16rne(a.y); r[2]=(short)bf16rne(a.z); r[3]=(short)bf16rne(a.w);
    r[4]=(short)bf16rne(b.x); r[5]=(short)bf16rne(b.y); r[6]=(short)bf16rne(b.z); r[7]=(short)bf16rne(b.w);
    return r;
}
__device__ __forceinline__ short8 cvt8(const float* p) {
    return pack8(*(const float4*)p, *(const float4*)(p + 4));
}
__device__ __forceinline__ unsigned long long ald64(const unsigned long long* p) {
    return __hip_atomic_load(p, __ATOMIC_RELAXED, __HIP_MEMORY_SCOPE_AGENT);
}

__global__ __launch_bounds__(NTHR, 1)
void gru_mfma(const float* __restrict__ x,
              const float* __restrict__ Wih,
              const float* __restrict__ Whh,
              const float* __restrict__ bih,
              const float* __restrict__ bhh,
              unsigned int* __restrict__ hslab,   // [2][128][256] u32 (bf16 pairs)
              unsigned int* __restrict__ flags)   // [1024][8][16]
{
    __shared__ __align__(16) float CB[8][4][256];   // [wave][acc][lane*4+reg] = 32 KB

    const int tid  = threadIdx.x;
    const int lane = tid & 63;
    const int g    = blockIdx.x >> 4;          // batch group 0..7
    const int cg   = blockIdx.x & 15;          // column group 0..15
    const int rb0  = g * ROWS;
    const int hc0  = cg * HC;

    const int wv = tid >> 6;                   // 0..7
    const int nh = wv & 1;                     // col half (16 cols)
    const int kq = wv >> 1;                    // K quarter

    // ---- one-time: weight B-fragments into registers ----
    const int coln = hc0 + nh * 16 + (lane & 15);
    short8 BX[2][3], BH[4][3];
#pragma unroll
    for (int xk = 0; xk < 2; ++xk) {
        int kb = kq * 64 + xk * 32 + ((lane >> 4) << 3);
#pragma unroll
        for (int nt = 0; nt < 3; ++nt)
            BX[xk][nt] = cvt8(Wih + (nt * H_ + coln) * I_ + kb);
    }
#pragma unroll
    for (int hk = 0; hk < 4; ++hk) {
        int kb = kq * 128 + hk * 32 + ((lane >> 4) << 3);
#pragma unroll
        for (int nt = 0; nt < 3; ++nt)
            BH[hk][nt] = cvt8(Whh + (nt * H_ + coln) * H_ + kb);
    }

    // A-frag geometry (single 16-row M-tile)
    const int arow = rb0 + (lane & 15);
    const int hfo  = arow * (H_ / 2) + ((lane >> 4) << 2);   // u32 idx; + kt*16

    // finalize: thread owns output (frow, fcl)
    const int frow = tid >> 5;                 // 0..15
    const int fcl  = tid & 31;                 // 0..31
    const int j    = hc0 + fcl;
    const float bR  = bih[j] + bhh[j];
    const float bZ  = bih[H_ + j] + bhh[H_ + j];
    const float bNx = bih[2 * H_ + j];
    const float bNh = bhh[2 * H_ + j];
    const int nh_f  = fcl >> 4;
    const int fbase = ((((frow >> 2) << 4) | (fcl & 15)) << 2) + (frow & 3);
    float hprev = 0.f;

    // x prefetch: this wave's 2 k-tiles (16 floats)
    const float* xptr = x + (arow * T_) * I_ + kq * 64 + ((lane >> 4) << 3);
    float4 px[4];
    px[0] = *(const float4*)xptr;        px[1] = *(const float4*)(xptr + 4);
    px[2] = *(const float4*)(xptr + 32); px[3] = *(const float4*)(xptr + 36);
    xptr += I_;

#pragma unroll 1
    for (int t = 0; t < T_; ++t) {
        // ---- A: wave0 polls the 16 group flags from step t-1 ----
        if (t > 0 && tid < 64) {
            const unsigned int* fl = flags + ((t - 1) * BGROUPS + g) * CGROUPS;
            unsigned int fv;
            do {
                fv = __hip_atomic_load(fl + (lane & 15), __ATOMIC_RELAXED, __HIP_MEMORY_SCOPE_AGENT);
            } while (!__all((int)(fv != 0)));
        }
        __syncthreads();

        // ---- B: h fragment loads (flag guarantees data landed) ----
        const unsigned int* hb = hslab + (t & 1) * HSLAB32 + hfo;
        unsigned long long hv[8];
#pragma unroll
        for (int hk = 0; hk < 4; ++hk) {
            const unsigned long long* p = (const unsigned long long*)(hb + (kq * 4 + hk) * 16);
            hv[2*hk]   = ald64(p);
            hv[2*hk+1] = ald64(p + 1);
        }

        // ---- C: x-part MFMAs while h loads fly ----
        f32x4 accR = {0.f,0.f,0.f,0.f}, accZ = accR, accNX = accR, accNH = accR;
#pragma unroll
        for (int xk = 0; xk < 2; ++xk) {
            short8 ax = pack8(px[2*xk], px[2*xk+1]);
            accR  = __builtin_amdgcn_mfma_f32_16x16x32_bf16(ax, BX[xk][0], accR, 0, 0, 0);
            accZ  = __builtin_amdgcn_mfma_f32_16x16x32_bf16(ax, BX[xk][1], accZ, 0, 0, 0);
            accNX = __builtin_amdgcn_mfma_f32_16x16x32_bf16(ax, BX[xk][2], accNX, 0, 0, 0);
        }
        // ---- D: h-part MFMAs ----
#pragma unroll
        for (int hk = 0; hk < 4; ++hk) {
            union { unsigned long long q[2]; short8 s; } u;
            u.q[0] = hv[2*hk]; u.q[1] = hv[2*hk+1];
            accR  = __builtin_amdgcn_mfma_f32_16x16x32_bf16(u.s, BH[hk][0], accR, 0, 0, 0);
            accZ  = __builtin_amdgcn_mfma_f32_16x16x32_bf16(u.s, BH[hk][1], accZ, 0, 0, 0);
            accNH = __builtin_amdgcn_mfma_f32_16x16x32_bf16(u.s, BH[hk][2], accNH, 0, 0, 0);
        }

        // ---- E: dump partials (linear frag layout) ----
        {
            float* cb = &CB[wv][0][0] + lane * 4;
            *(f32x4*)(cb +   0) = accR;
            *(f32x4*)(cb + 256) = accZ;
            *(f32x4*)(cb + 512) = accNX;
            *(f32x4*)(cb + 768) = accNH;
        }
        __syncthreads();

        // ---- F: finalize: sum 4 K-quarters, gates, store bf16 pair ----
        {
            float sr = bR, sz = bZ, sxn = bNx, shn = bNh;
#pragma unroll
            for (int q = 0; q < 4; ++q) {
                const float* cb = &CB[q * 2 + nh_f][0][0] + fbase;
                sr  += cb[0];
                sz  += cb[256];
                sxn += cb[512];
                shn += cb[768];
            }
            float r = 1.f / (1.f + __expf(-sr));
            float z = 1.f / (1.f + __expf(-sz));
            float e2 = __expf(2.f * (sxn + r * shn));
            float n = 1.f - 2.f / (e2 + 1.f);          // tanh, overflow-safe
            float hnew = (1.f - z) * n + z * hprev;
            hprev = hnew;
            unsigned int hb16 = bf16rne(hnew);
            unsigned int ob = (unsigned int)__shfl_xor((int)hb16, 1);
            if (!(fcl & 1)) {
                __hip_atomic_store(hslab + ((t + 1) & 1) * HSLAB32 + (rb0 + frow) * (H_ / 2) + (j >> 1),
                                   (hb16 & 0xffffu) | (ob << 16),
                                   __ATOMIC_RELAXED, __HIP_MEMORY_SCOPE_AGENT);
            }
        }

        // ---- G: drain all stores (syncthreads emits vmcnt(0)), then flag ----
        __syncthreads();
        if (tid == 0)
            __hip_atomic_store(flags + (t * BGROUPS + g) * CGROUPS + cg, 1u,
                               __ATOMIC_RELAXED, __HIP_MEMORY_SCOPE_AGENT);

        // ---- H: prefetch x(t+1); latency hides under next detect ----
        if (t + 1 < T_) {
            px[0] = *(const float4*)xptr;        px[1] = *(const float4*)(xptr + 4);
            px[2] = *(const float4*)(xptr + 32); px[3] = *(const float4*)(xptr + 36);
            xptr += I_;
        }
    }
}

__global__ __launch_bounds__(256)
void fc_kernel(const unsigned int* __restrict__ hp,   // hslab[0]: [128][256] u32 bf16-pairs
               const float* __restrict__ fcW,
               const float* __restrict__ fcb,
               float* __restrict__ out)
{
    int gid = blockIdx.x * 256 + threadIdx.x;
    int b = gid >> 7, o = gid & 127;
    const unsigned int* hr = hp + b * (H_ / 2);
    const float* wr = fcW + o * H_;
    float acc = 0.f;
#pragma unroll 8
    for (int i = 0; i < H_ / 2; i += 4) {
        uint4 v = *(const uint4*)(hr + i);
        float4 w0 = *(const float4*)(wr + 2 * i);
        float4 w1 = *(const float4*)(wr + 2 * i + 4);
        acc += __builtin_bit_cast(float, v.x << 16)          * w0.x
             + __builtin_bit_cast(float, v.x & 0xffff0000u)  * w0.y
             + __builtin_bit_cast(float, v.y << 16)          * w0.z
             + __builtin_bit_cast(float, v.y & 0xffff0000u)  * w0.w
             + __builtin_bit_cast(float, v.z << 16)          * w1.x
             + __builtin_bit_cast(float, v.z & 0xffff0000u)  * w1.y
             + __builtin_bit_cast(float, v.w << 16)          * w1.z
             + __builtin_bit_cast(float, v.w & 0xffff0000u)  * w1.w;
    }
    out[gid] = acc + fcb[o];
}

extern "C" void kernel_launch(void* const* d_in, const int* in_sizes, int n_in,
                              void* d_out, int out_size, void* d_ws, size_t ws_size,
                              hipStream_t stream)
{
    const float* x   = (const float*)d_in[0];
    const float* Wih = (const float*)d_in[1];
    const float* Whh = (const float*)d_in[2];
    const float* bih = (const float*)d_in[3];
    const float* bhh = (const float*)d_in[4];
    const float* fcW = (const float*)d_in[5];
    const float* fcb = (const float*)d_in[6];
    float* out = (float*)d_out;

    unsigned int* hslab = (unsigned int*)d_ws;            // [2][128][256]
    unsigned int* flags = hslab + 2 * HSLAB32;            // [1024][8][16]

    hipMemsetAsync(d_ws, 0, WS_INIT_BYTES, stream);       // h0 = 0, flags = 0 (every replay)

    hipLaunchKernelGGL(gru_mfma, dim3(NBLK), dim3(NTHR), 0, stream,
                       x, Wih, Whh, bih, bhh, hslab, flags);

    hipLaunchKernelGGL(fc_kernel, dim3((B_ * O_) / 256), dim3(256), 0, stream,
                       hslab, fcW, fcb, out);             // final h is slab 0 (T even)
}